// Round 1
// 272.709 us; speedup vs baseline: 1.0558x; 1.0558x over previous
//
#include <hip/hip_runtime.h>
#include <hip/hip_bf16.h>

#define S_LEN 2048
#define DMODEL 1024
#define NHEAD 16
#define DKEY 64

typedef __attribute__((ext_vector_type(8))) short bf16x8;
typedef __attribute__((ext_vector_type(4))) float f32x4;

__device__ __forceinline__ short f2bf(float f) {
  union { float f; unsigned u; } a; a.f = f;
  unsigned u = a.u;
  u += 0x7fff + ((u >> 16) & 1);   // RTNE
  return (short)(u >> 16);
}
__device__ __forceinline__ unsigned pk2bf(float a, float b) {
  union { __hip_bfloat162 h; unsigned u; } c;
  c.h = __float22bfloat162_rn(float2{a, b});
  return c.u;
}
__device__ __forceinline__ void gl_lds16(const void* g, void* l) {
  __builtin_amdgcn_global_load_lds(
      (const __attribute__((address_space(1))) unsigned int*)g,
      (__attribute__((address_space(3))) unsigned int*)l, 16, 0, 0);
}
#define EX2(x) __builtin_amdgcn_exp2f(x)

// ---------------------------------------------------------------------------
// Kernel -1: X (q,k,v) fp32 -> bf16, elementwise. grid (4096, 3) x 256.
// ---------------------------------------------------------------------------
__global__ __launch_bounds__(256) void convert_x(
    const float* __restrict__ q, const float* __restrict__ k,
    const float* __restrict__ v, short* __restrict__ Xb) {
  const int z = blockIdx.y;
  const float* X = (z == 0) ? q : (z == 1) ? k : v;
  short* dst = Xb + (size_t)z * 4194304;
  const int i = (blockIdx.x * 256 + threadIdx.x) * 4;
  const float4 xv = *(const float4*)&X[i];
  uint2 o;
  o.x = pk2bf(xv.x, xv.y);
  o.y = pk2bf(xv.z, xv.w);
  *(uint2*)&dst[i] = o;
}

// ---------------------------------------------------------------------------
// Kernel 0: weight transpose+convert. W[k][n] f32 -> Wt[n][k] bf16, 4 weights.
// ---------------------------------------------------------------------------
__global__ __launch_bounds__(256) void convert_w(
    const float* __restrict__ Wq, const float* __restrict__ Wk,
    const float* __restrict__ Wv, const float* __restrict__ Wo,
    short* __restrict__ Wt) {
  __shared__ short T[64][72];
  const int z = blockIdx.z;
  const float* W = (z == 0) ? Wq : (z == 1) ? Wk : (z == 2) ? Wv : Wo;
  short* dst = Wt + (size_t)z * 1048576;
  const int k0 = blockIdx.x * 64, n0 = blockIdx.y * 64;
  const int t = threadIdx.x;
#pragma unroll
  for (int p = 0; p < 4; ++p) {
    const int r = p * 16 + (t >> 4), c = (t & 15) * 4;
    const float4 wv = *(const float4*)&W[(size_t)(k0 + r) * DMODEL + n0 + c];
    T[c + 0][r] = f2bf(wv.x);
    T[c + 1][r] = f2bf(wv.y);
    T[c + 2][r] = f2bf(wv.z);
    T[c + 3][r] = f2bf(wv.w);
  }
  __syncthreads();
  const int rr = t >> 2, cc = (t & 3) * 16;
  const bf16x8 x0 = *(const bf16x8*)&T[rr][cc];
  const bf16x8 x1 = *(const bf16x8*)&T[rr][cc + 8];
  short* d = dst + (size_t)(n0 + rr) * DMODEL + k0 + cc;
  *(bf16x8*)&d[0] = x0;
  *(bf16x8*)&d[8] = x1;
}

// ---------------------------------------------------------------------------
// Bf16 tile staging with bank-conflict-free XOR chunk swizzle.
// ---------------------------------------------------------------------------
__device__ __forceinline__ void stage_tile32(const short* gbase, short (*tile)[32],
                                             int w, int lane) {
  const int row = lane >> 2;                          // 0..15 per issue
  const int g = ((lane & 3) ^ ((row >> 1) & 3)) * 8;  // swizzled global chunk
#pragma unroll
  for (int i = 0; i < 2; ++i) {
    const int r = w * 32 + i * 16 + row;
    gl_lds16(gbase + (size_t)r * DMODEL + g, &tile[w * 32 + i * 16][0]);
  }
}

// ---------------------------------------------------------------------------
// Kernel 1: QKV projection, 128x128 tile, BK=32, all-bf16, swizzled LDS.
// z=0 Q (RoPE + exp2-domain scale -> [bh][s][dk]), z=1 K (RoPE), z=2 V^T.
// ---------------------------------------------------------------------------
__global__ __launch_bounds__(256) void gemm_qkv(
    const short* __restrict__ Xb, const short* __restrict__ Wt,
    const float* __restrict__ bq, const float* __restrict__ bk,
    const float* __restrict__ bv, const float* __restrict__ rope,
    short* __restrict__ Qw, short* __restrict__ Kw, short* __restrict__ Vw) {
  __shared__ char smem[36864];                     // 36 KB (epilogue reuse)
  short (*As)[32] = (short(*)[32])smem;            // 128x32 bf16, 8 KB
  short (*Bs)[32] = (short(*)[32])(smem + 8192);   // 128x32 bf16, 8 KB

  const int z = blockIdx.z;
  const short* X = Xb + (size_t)z * 4194304;
  const float* bias = (z == 0) ? bq : (z == 1) ? bk : bv;
  const short* Wz = Wt + (size_t)z * 1048576;

  const int m0 = blockIdx.x * 128, n0 = blockIdx.y * 128;
  const int t = threadIdx.x;
  const int lane = t & 63;
  const int w = t >> 6;
  const int quad = lane >> 4;
  const int l15 = lane & 15;
  const int wr = (w >> 1) * 64, wc = (w & 1) * 64;
  const int rswz = (quad ^ ((l15 >> 1) & 3)) * 8;  // frag-read swizzled offset

  f32x4 acc[4][4] = {};

  for (int kt = 0; kt < DMODEL; kt += 32) {
    __syncthreads();
    stage_tile32(X + (size_t)m0 * DMODEL + kt, As, w, lane);
    stage_tile32(Wz + (size_t)n0 * DMODEL + kt, Bs, w, lane);
    __syncthreads();
    bf16x8 bf[4], af[4];
#pragma unroll
    for (int nj = 0; nj < 4; ++nj)
      bf[nj] = *(const bf16x8*)&Bs[wc + nj * 16 + l15][rswz];
#pragma unroll
    for (int mi = 0; mi < 4; ++mi)
      af[mi] = *(const bf16x8*)&As[wr + mi * 16 + l15][rswz];
#pragma unroll
    for (int mi = 0; mi < 4; ++mi)
#pragma unroll
      for (int nj = 0; nj < 4; ++nj)
        acc[mi][nj] =
            __builtin_amdgcn_mfma_f32_16x16x32_bf16(af[mi], bf[nj], acc[mi][nj], 0, 0, 0);
  }

  const int b = (m0 + wr) >> 11;
  const int sbase = (m0 + wr) & 2047;

  if (z == 2) {
    __syncthreads();
    short (*tr)[72] = (short(*)[72])(smem + w * 9216);
    const int h = (n0 + wc) >> 6;
#pragma unroll
    for (int nj = 0; nj < 4; ++nj) {
      const float bval = bias[n0 + wc + nj * 16 + l15];
#pragma unroll
      for (int ti = 0; ti < 4; ++ti)
#pragma unroll
        for (int r = 0; r < 4; ++r)
          tr[nj * 16 + l15][ti * 16 + quad * 4 + r] = f2bf(acc[ti][nj][r] + bval);
    }
    asm volatile("s_waitcnt lgkmcnt(0)" ::: "memory");
    const int bh = b * NHEAD + h;
#pragma unroll
    for (int cc = 0; cc < 4; ++cc) {
      const int row = cc * 16 + (lane >> 2);
      const int c0 = (lane & 3) * 16;
      const bf16x8 x0 = *(const bf16x8*)&tr[row][c0];
      const bf16x8 x1 = *(const bf16x8*)&tr[row][c0 + 8];
      short* d = Vw + ((size_t)bh * DKEY + row) * S_LEN + sbase + c0;
      *(bf16x8*)&d[0] = x0;
      *(bf16x8*)&d[8] = x1;
    }
    return;
  }

  short* outw = (z == 0) ? Qw : Kw;
#pragma unroll
  for (int nj = 0; nj < 4; ++nj) {
    const int n = n0 + wc + nj * 16 + l15;
    const float bval = bias[n];
    const int h = n >> 6, dk = n & 63;
    const int bh = b * NHEAD + h;
#pragma unroll
    for (int ti = 0; ti < 4; ++ti) {
#pragma unroll
      for (int r = 0; r < 4; ++r) {
        const int s = sbase + ti * 16 + quad * 4 + r;
        float val = acc[ti][nj][r] + bval;
        const float cosv = rope[((size_t)b * S_LEN + s) * DKEY + (dk | 1)];
        const float sinv = rope[((size_t)b * S_LEN + s) * DKEY + (dk & ~1)];
        const float partner = __shfl_xor(val, 1);
        val = (dk & 1) ? (val * cosv + partner * sinv)
                       : (val * cosv - partner * sinv);
        // (1/8)*log2(e): softmax runs in exp2 domain inside attn_kernel.
        if (z == 0) val *= 0.18033688011112042f;
        outw[((size_t)bh * S_LEN + s) * DKEY + dk] = f2bf(val);
      }
    }
  }
}

// ---------------------------------------------------------------------------
// Kernel 2: causal flash attention, rebuilt for VALU economy + occupancy.
//  - grid (32, 32): one 64-row q-chunk per block; balanced chunk map so the 4
//    co-resident blocks per CU (dispatch d, d+256, d+512, d+768 share
//    blockIdx.x) get chunks {x, x^31, x^16, x^31^16} -> constant 66 iters/CU.
//  - LDS exactly 40960 B (Kt 16K + Vt 16K + Sb 8K XOR-swizzled) -> 4 blk/CU.
//  - exp2-domain softmax (Q pre-scaled by log2e/8), defer-max rescale,
//    diagonal-only causal mask, block-uniform v_mask fast path, setprio.
// ---------------------------------------------------------------------------
__global__ __launch_bounds__(256, 4) void attn_kernel(
    const short* __restrict__ Qw, const short* __restrict__ Kw,
    const short* __restrict__ Vw, const float* __restrict__ v_mask,
    short* __restrict__ Ow) {
  __shared__ short Kt[2][64][64];
  __shared__ short Vt[2][64][64];
  __shared__ short Sb[4][16][64];   // XOR chunk-swizzled: chunk ^= (row & 7)

  const int t = threadIdx.x;
  const int w = t >> 6;
  const int lane = t & 63;
  const int quad = lane >> 4;
  const int l15 = lane & 15;
  const int x8 = l15 & 7;
  const int bh = blockIdx.y;
  const int b = bh >> 4;
  const int h = bh & 15;

  // balanced chunk map (see header comment)
  int c = blockIdx.x;
  const int jj = blockIdx.y >> 3;
  if (jj & 1) c ^= 31;
  if (jj & 2) c ^= 16;

  const short* Kbase = Kw + (size_t)bh * S_LEN * DKEY;
  const short* Vbase = Vw + (size_t)bh * DKEY * S_LEN;
  const float* vmb = v_mask + (size_t)b * S_LEN;

  const int sRow = lane >> 3;
  const int sCh = (lane & 7) ^ sRow;

  const int qb = c * 64;
  const int qrow = qb + w * 16 + l15;

  const short* Qp = Qw + ((size_t)bh * S_LEN + qrow) * DKEY;
  const bf16x8 q_lo = *(const bf16x8*)(Qp + quad * 8);
  const bf16x8 q_hi = *(const bf16x8*)(Qp + 32 + quad * 8);

  // block-uniform v_mask shortcut: exact iff every element == 1.0f
  float s32 = 0.f;
  {
    const float4* vm4 = (const float4*)vmb;
#pragma unroll
    for (int i = 0; i < 8; ++i) {
      const float4 a = vm4[lane * 8 + i];
      s32 += a.x + a.y + a.z + a.w;
    }
  }
  const bool vmall = __all(s32 == 32.0f);

  float m_i = -1.0e30f, l_i = 0.f;
  f32x4 acc[4] = {};

  const int niter = c + 1;
#pragma unroll
  for (int i = 0; i < 2; ++i) {
    const int kr = w * 16 + i * 8 + sRow;
    gl_lds16(Kbase + (size_t)kr * DKEY + sCh * 8, &Kt[0][w * 16 + i * 8][0]);
    gl_lds16(Vbase + (size_t)kr * S_LEN + sCh * 8, &Vt[0][w * 16 + i * 8][0]);
  }
  int cur = 0;
  for (int it = 0; it < niter; ++it) {
    const int j0 = it * 64;
    __syncthreads();
    if (it + 1 < niter) {
      const int jn = j0 + 64;
#pragma unroll
      for (int i = 0; i < 2; ++i) {
        const int kr = w * 16 + i * 8 + sRow;
        gl_lds16(Kbase + (size_t)(jn + kr) * DKEY + sCh * 8,
                 &Kt[cur ^ 1][w * 16 + i * 8][0]);
        gl_lds16(Vbase + (size_t)kr * S_LEN + jn + sCh * 8,
                 &Vt[cur ^ 1][w * 16 + i * 8][0]);
      }
    }
    bf16x8 ka[4][2];
#pragma unroll
    for (int kt = 0; kt < 4; ++kt) {
      ka[kt][0] = *(const bf16x8*)&Kt[cur][kt * 16 + l15][(quad ^ x8) * 8];
      ka[kt][1] = *(const bf16x8*)&Kt[cur][kt * 16 + l15][((4 + quad) ^ x8) * 8];
    }
    f32x4 sv[4];
    __builtin_amdgcn_s_setprio(1);
#pragma unroll
    for (int kt = 0; kt < 4; ++kt) {
      f32x4 s = {};
      s = __builtin_amdgcn_mfma_f32_16x16x32_bf16(ka[kt][0], q_lo, s, 0, 0, 0);
      s = __builtin_amdgcn_mfma_f32_16x16x32_bf16(ka[kt][1], q_hi, s, 0, 0, 0);
      sv[kt] = s;
    }
    __builtin_amdgcn_s_setprio(0);
    if (!vmall) {
#pragma unroll
      for (int kt = 0; kt < 4; ++kt) {
        const float4 vm = *(const float4*)&vmb[j0 + kt * 16 + quad * 4];
#pragma unroll
        for (int r = 0; r < 4; ++r)
          sv[kt][r] += (vm[r] - 1.0f) * 1.0e12f;
      }
    }
    if (it == c) {  // diagonal tile: only place causal mask can trigger
#pragma unroll
      for (int kt = 0; kt < 4; ++kt)
#pragma unroll
        for (int r = 0; r < 4; ++r) {
          const int kc = j0 + kt * 16 + quad * 4 + r;
          if (kc > qrow) sv[kt][r] = -1.0e12f;
        }
    }
    // local max (tree), then cross-quad max
    float mk[4];
#pragma unroll
    for (int kt = 0; kt < 4; ++kt)
      mk[kt] = fmaxf(fmaxf(sv[kt][0], sv[kt][1]), fmaxf(sv[kt][2], sv[kt][3]));
    const float mloc = fmaxf(fmaxf(mk[0], mk[1]), fmaxf(mk[2], mk[3]));
    float mt = fmaxf(mloc, __shfl_xor(mloc, 16));
    mt = fmaxf(mt, __shfl_xor(mt, 32));
    // defer-max: only rescale when the running max grew by > 8 (2^8 headroom)
    if (!__all(mt <= m_i + 8.0f)) {
      const float mn = fmaxf(m_i, mt);
      const float alpha = EX2(m_i - mn);
      l_i *= alpha;
#pragma unroll
      for (int dt = 0; dt < 4; ++dt)
#pragma unroll
        for (int r = 0; r < 4; ++r) acc[dt][r] *= alpha;
      m_i = mn;
    }
    // p = 2^(s - m_i) directly (pscale folded); row-sum
    float sl = 0.f;
#pragma unroll
    for (int kt = 0; kt < 4; ++kt)
#pragma unroll
      for (int r = 0; r < 4; ++r) {
        sv[kt][r] = EX2(sv[kt][r] - m_i);
        sl += sv[kt][r];
      }
    sl += __shfl_xor(sl, 16);
    sl += __shfl_xor(sl, 32);
    l_i += sl;
    // pack P into XOR-swizzled Sb, reread as MFMA B-fragments
#pragma unroll
    for (int kt = 0; kt < 4; ++kt) {
      uint2 pw;
      pw.x = pk2bf(sv[kt][0], sv[kt][1]);
      pw.y = pk2bf(sv[kt][2], sv[kt][3]);
      *(uint2*)&Sb[w][l15][(((2 * kt + (quad >> 1)) ^ x8) * 8) + (quad & 1) * 4] = pw;
    }
    asm volatile("s_waitcnt lgkmcnt(0)" ::: "memory");
    const bf16x8 pf0 = *(const bf16x8*)&Sb[w][l15][(quad ^ x8) * 8];
    const bf16x8 pf1 = *(const bf16x8*)&Sb[w][l15][((4 + quad) ^ x8) * 8];
    __builtin_amdgcn_s_setprio(1);
#pragma unroll
    for (int dt = 0; dt < 4; ++dt) {
      const bf16x8 va0 =
          *(const bf16x8*)&Vt[cur][dt * 16 + l15][(quad ^ x8) * 8];
      acc[dt] = __builtin_amdgcn_mfma_f32_16x16x32_bf16(va0, pf0, acc[dt], 0, 0, 0);
      const bf16x8 va1 =
          *(const bf16x8*)&Vt[cur][dt * 16 + l15][((4 + quad) ^ x8) * 8];
      acc[dt] = __builtin_amdgcn_mfma_f32_16x16x32_bf16(va1, pf1, acc[dt], 0, 0, 0);
    }
    __builtin_amdgcn_s_setprio(0);
    cur ^= 1;
  }
  // epilogue: normalize, stage through swizzled Sb, coalesced store
  const float inv = 1.0f / l_i;
#pragma unroll
  for (int dt = 0; dt < 4; ++dt) {
    uint2 ov;
    ov.x = pk2bf(acc[dt][0] * inv, acc[dt][1] * inv);
    ov.y = pk2bf(acc[dt][2] * inv, acc[dt][3] * inv);
    *(uint2*)&Sb[w][l15][(((2 * dt + (quad >> 1)) ^ x8) * 8) + (quad & 1) * 4] = ov;
  }
  asm volatile("s_waitcnt lgkmcnt(0)" ::: "memory");
  const int qr2 = lane >> 2;
  const int cc2 = lane & 3;
  const bf16x8 o0 = *(const bf16x8*)&Sb[w][qr2][((2 * cc2) ^ (qr2 & 7)) * 8];
  const bf16x8 o1 = *(const bf16x8*)&Sb[w][qr2][((2 * cc2 + 1) ^ (qr2 & 7)) * 8];
  short* dst =
      Ow + ((size_t)(b * S_LEN + qb + w * 16 + qr2)) * DMODEL + h * DKEY + cc2 * 16;
  *(bf16x8*)&dst[0] = o0;
  *(bf16x8*)&dst[8] = o1;
}

// ---------------------------------------------------------------------------
// Kernel 3: output projection, swizzled bf16 tiles. fp32 out + bias.
// ---------------------------------------------------------------------------
__global__ __launch_bounds__(256) void gemm_out(
    const short* __restrict__ A, const short* __restrict__ Wz,
    const float* __restrict__ bias, float* __restrict__ out) {
  __shared__ char smem[16384];
  short (*As)[32] = (short(*)[32])smem;
  short (*Bs)[32] = (short(*)[32])(smem + 8192);

  const int m0 = blockIdx.x * 128, n0 = blockIdx.y * 128;
  const int t = threadIdx.x;
  const int lane = t & 63;
  const int w = t >> 6;
  const int quad = lane >> 4;
  const int l15 = lane & 15;
  const int wr = (w >> 1) * 64, wc = (w & 1) * 64;
  const int rswz = (quad ^ ((l15 >> 1) & 3)) * 8;

  f32x4 acc[4][4] = {};

  for (int kt = 0; kt < DMODEL; kt += 32) {
    __syncthreads();
    stage_tile32(A + (size_t)m0 * DMODEL + kt, As, w, lane);
    stage_tile32(Wz + (size_t)n0 * DMODEL + kt, Bs, w, lane);
    __syncthreads();
    bf16x8 bf[4], af[4];
#pragma unroll
    for (int nj = 0; nj < 4; ++nj)
      bf[nj] = *(const bf16x8*)&Bs[wc + nj * 16 + l15][rswz];
#pragma unroll
    for (int mi = 0; mi < 4; ++mi)
      af[mi] = *(const bf16x8*)&As[wr + mi * 16 + l15][rswz];
#pragma unroll
    for (int mi = 0; mi < 4; ++mi)
#pragma unroll
      for (int nj = 0; nj < 4; ++nj)
        acc[mi][nj] =
            __builtin_amdgcn_mfma_f32_16x16x32_bf16(af[mi], bf[nj], acc[mi][nj], 0, 0, 0);
  }
#pragma unroll
  for (int nj = 0; nj < 4; ++nj) {
    const int n = n0 + wc + nj * 16 + l15;
    const float bval = bias[n];
#pragma unroll
    for (int ti = 0; ti < 4; ++ti)
#pragma unroll
      for (int r = 0; r < 4; ++r) {
        const int m = m0 + wr + ti * 16 + quad * 4 + r;
        out[(size_t)m * DMODEL + n] = acc[ti][nj][r] + bval;
      }
  }
}

// ---------------------------------------------------------------------------
extern "C" void kernel_launch(void* const* d_in, const int* in_sizes, int n_in,
                              void* d_out, int out_size, void* d_ws,
                              size_t ws_size, hipStream_t stream) {
  const float* q      = (const float*)d_in[0];
  const float* k      = (const float*)d_in[1];
  const float* v      = (const float*)d_in[2];
  const float* rope   = (const float*)d_in[3];
  const float* v_mask = (const float*)d_in[5];
  const float* Wq = (const float*)d_in[6];
  const float* bq = (const float*)d_in[7];
  const float* Wk = (const float*)d_in[8];
  const float* bk = (const float*)d_in[9];
  const float* Wv = (const float*)d_in[10];
  const float* bv = (const float*)d_in[11];
  const float* Wo = (const float*)d_in[12];
  const float* bo = (const float*)d_in[13];
  float* out = (float*)d_out;

  short* ws = (short*)d_ws;
  short* Qw = ws;                  // [bh][s][dk] bf16, 8 MB
  short* Kw = ws + 4194304;        // [bh][s][dk] bf16, 8 MB
  short* Vw = ws + 8388608;        // [bh][dk][s] bf16, 8 MB
  short* Ow = ws + 12582912;       // [b][s][dmodel] bf16, 8 MB
  short* Wt = ws + 16777216;       // 4x [n][k] bf16, 8 MB
  short* Xb = ws + 20971520;       // 3x [m][k] bf16, 24 MB  (total 64 MB)

  convert_x<<<dim3(4096, 3), 256, 0, stream>>>(q, k, v, Xb);
  convert_w<<<dim3(16, 16, 4), 256, 0, stream>>>(Wq, Wk, Wv, Wo, Wt);
  gemm_qkv<<<dim3(32, 8, 3), 256, 0, stream>>>(Xb, Wt, bq, bk, bv, rope,
                                               Qw, Kw, Vw);
  attn_kernel<<<dim3(32, 32), 256, 0, stream>>>(Qw, Kw, Vw, v_mask, Ow);
  gemm_out<<<dim3(32, 8), 256, 0, stream>>>(Ow, Wt + 3145728, bo, out);
}

// Round 2
// 247.572 us; speedup vs baseline: 1.1630x; 1.1015x over previous
//
#include <hip/hip_runtime.h>
#include <hip/hip_bf16.h>

#define S_LEN 2048
#define DMODEL 1024
#define NHEAD 16
#define DKEY 64

typedef __attribute__((ext_vector_type(8))) short bf16x8;
typedef __attribute__((ext_vector_type(4))) float f32x4;

__device__ __forceinline__ short f2bf(float f) {
  union { float f; unsigned u; } a; a.f = f;
  unsigned u = a.u;
  u += 0x7fff + ((u >> 16) & 1);   // RTNE
  return (short)(u >> 16);
}
__device__ __forceinline__ unsigned pk2bf(float a, float b) {
  union { __hip_bfloat162 h; unsigned u; } c;
  c.h = __float22bfloat162_rn(float2{a, b});
  return c.u;
}
__device__ __forceinline__ void gl_lds16(const void* g, void* l) {
  __builtin_amdgcn_global_load_lds(
      (const __attribute__((address_space(1))) unsigned int*)g,
      (__attribute__((address_space(3))) unsigned int*)l, 16, 0, 0);
}
#define EX2(x) __builtin_amdgcn_exp2f(x)

// ---------------------------------------------------------------------------
// Kernel -1: X (q,k,v) fp32 -> bf16, elementwise. grid (4096, 3) x 256.
// ---------------------------------------------------------------------------
__global__ __launch_bounds__(256) void convert_x(
    const float* __restrict__ q, const float* __restrict__ k,
    const float* __restrict__ v, short* __restrict__ Xb) {
  const int z = blockIdx.y;
  const float* X = (z == 0) ? q : (z == 1) ? k : v;
  short* dst = Xb + (size_t)z * 4194304;
  const int i = (blockIdx.x * 256 + threadIdx.x) * 4;
  const float4 xv = *(const float4*)&X[i];
  uint2 o;
  o.x = pk2bf(xv.x, xv.y);
  o.y = pk2bf(xv.z, xv.w);
  *(uint2*)&dst[i] = o;
}

// ---------------------------------------------------------------------------
// Kernel 0: weight transpose+convert. W[k][n] f32 -> Wt[n][k] bf16, 4 weights.
// ---------------------------------------------------------------------------
__global__ __launch_bounds__(256) void convert_w(
    const float* __restrict__ Wq, const float* __restrict__ Wk,
    const float* __restrict__ Wv, const float* __restrict__ Wo,
    short* __restrict__ Wt) {
  __shared__ short T[64][72];
  const int z = blockIdx.z;
  const float* W = (z == 0) ? Wq : (z == 1) ? Wk : (z == 2) ? Wv : Wo;
  short* dst = Wt + (size_t)z * 1048576;
  const int k0 = blockIdx.x * 64, n0 = blockIdx.y * 64;
  const int t = threadIdx.x;
#pragma unroll
  for (int p = 0; p < 4; ++p) {
    const int r = p * 16 + (t >> 4), c = (t & 15) * 4;
    const float4 wv = *(const float4*)&W[(size_t)(k0 + r) * DMODEL + n0 + c];
    T[c + 0][r] = f2bf(wv.x);
    T[c + 1][r] = f2bf(wv.y);
    T[c + 2][r] = f2bf(wv.z);
    T[c + 3][r] = f2bf(wv.w);
  }
  __syncthreads();
  const int rr = t >> 2, cc = (t & 3) * 16;
  const bf16x8 x0 = *(const bf16x8*)&T[rr][cc];
  const bf16x8 x1 = *(const bf16x8*)&T[rr][cc + 8];
  short* d = dst + (size_t)(n0 + rr) * DMODEL + k0 + cc;
  *(bf16x8*)&d[0] = x0;
  *(bf16x8*)&d[8] = x1;
}

// ---------------------------------------------------------------------------
// Bf16 tile staging with bank-conflict-free XOR chunk swizzle.
// Each thread issues exactly 2 global_load_lds (vmcnt += 2 per call).
// ---------------------------------------------------------------------------
__device__ __forceinline__ void stage_tile32(const short* gbase, short (*tile)[32],
                                             int w, int lane) {
  const int row = lane >> 2;                          // 0..15 per issue
  const int g = ((lane & 3) ^ ((row >> 1) & 3)) * 8;  // swizzled global chunk
#pragma unroll
  for (int i = 0; i < 2; ++i) {
    const int r = w * 32 + i * 16 + row;
    gl_lds16(gbase + (size_t)r * DMODEL + g, &tile[w * 32 + i * 16][0]);
  }
}

// ---------------------------------------------------------------------------
// Kernel 1: QKV projection, 128x128 tile, BK=32, all-bf16, swizzled LDS.
// 3-deep ring pipeline with counted vmcnt: tile t+1/t+2 loads stay in flight
// across the barrier (never drain to 0 in the main loop).
// z=0 Q (RoPE + exp2-domain scale -> [bh][s][dk]), z=1 K (RoPE), z=2 V^T.
// ---------------------------------------------------------------------------
__global__ __launch_bounds__(256) void gemm_qkv(
    const short* __restrict__ Xb, const short* __restrict__ Wt,
    const float* __restrict__ bq, const float* __restrict__ bk,
    const float* __restrict__ bv, const float* __restrict__ rope,
    short* __restrict__ Qw, short* __restrict__ Kw, short* __restrict__ Vw) {
  __shared__ char smem[49152];   // 3 ring buffers x (A 8KB + B 8KB)

  const int z = blockIdx.z;
  const short* X = Xb + (size_t)z * 4194304;
  const float* bias = (z == 0) ? bq : (z == 1) ? bk : bv;
  const short* Wz = Wt + (size_t)z * 1048576;

  const int m0 = blockIdx.x * 128, n0 = blockIdx.y * 128;
  const int t = threadIdx.x;
  const int lane = t & 63;
  const int w = t >> 6;
  const int quad = lane >> 4;
  const int l15 = lane & 15;
  const int wr = (w >> 1) * 64, wc = (w & 1) * 64;
  const int rswz = (quad ^ ((l15 >> 1) & 3)) * 8;  // frag-read swizzled offset

  const short* Abase = X + (size_t)m0 * DMODEL;
  const short* Bbase = Wz + (size_t)n0 * DMODEL;

  f32x4 acc[4][4] = {};

  // prologue: tiles 0 and 1 into ring slots 0,1
  stage_tile32(Abase + 0, (short(*)[32])(smem + 0), w, lane);
  stage_tile32(Bbase + 0, (short(*)[32])(smem + 8192), w, lane);
  stage_tile32(Abase + 32, (short(*)[32])(smem + 16384), w, lane);
  stage_tile32(Bbase + 32, (short(*)[32])(smem + 16384 + 8192), w, lane);

  unsigned oc = 0, on = 16384, of = 32768;   // cur / next / future offsets
  for (int it = 0; it < 32; ++it) {
    if (it < 30) {
      const int kt = (it + 2) * 32;
      stage_tile32(Abase + kt, (short(*)[32])(smem + of), w, lane);
      stage_tile32(Bbase + kt, (short(*)[32])(smem + of + 8192), w, lane);
    }
    if (it < 30)       asm volatile("s_waitcnt vmcnt(8)" ::: "memory");
    else if (it == 30) asm volatile("s_waitcnt vmcnt(4)" ::: "memory");
    else               asm volatile("s_waitcnt vmcnt(0)" ::: "memory");
    __builtin_amdgcn_s_barrier();
    short (*As)[32] = (short(*)[32])(smem + oc);
    short (*Bs)[32] = (short(*)[32])(smem + oc + 8192);
    bf16x8 bf[4], af[4];
#pragma unroll
    for (int nj = 0; nj < 4; ++nj)
      bf[nj] = *(const bf16x8*)&Bs[wc + nj * 16 + l15][rswz];
#pragma unroll
    for (int mi = 0; mi < 4; ++mi)
      af[mi] = *(const bf16x8*)&As[wr + mi * 16 + l15][rswz];
#pragma unroll
    for (int mi = 0; mi < 4; ++mi)
#pragma unroll
      for (int nj = 0; nj < 4; ++nj)
        acc[mi][nj] =
            __builtin_amdgcn_mfma_f32_16x16x32_bf16(af[mi], bf[nj], acc[mi][nj], 0, 0, 0);
    asm volatile("s_waitcnt lgkmcnt(0)" ::: "memory");
    __builtin_amdgcn_s_barrier();
    const unsigned tmp = oc; oc = on; on = of; of = tmp;
  }

  const int b = (m0 + wr) >> 11;
  const int sbase = (m0 + wr) & 2047;

  if (z == 2) {
    __syncthreads();
    short (*tr)[72] = (short(*)[72])(smem + w * 9216);
    const int h = (n0 + wc) >> 6;
#pragma unroll
    for (int nj = 0; nj < 4; ++nj) {
      const float bval = bias[n0 + wc + nj * 16 + l15];
#pragma unroll
      for (int ti = 0; ti < 4; ++ti)
#pragma unroll
        for (int r = 0; r < 4; ++r)
          tr[nj * 16 + l15][ti * 16 + quad * 4 + r] = f2bf(acc[ti][nj][r] + bval);
    }
    asm volatile("s_waitcnt lgkmcnt(0)" ::: "memory");
    const int bh = b * NHEAD + h;
#pragma unroll
    for (int cc = 0; cc < 4; ++cc) {
      const int row = cc * 16 + (lane >> 2);
      const int c0 = (lane & 3) * 16;
      const bf16x8 x0 = *(const bf16x8*)&tr[row][c0];
      const bf16x8 x1 = *(const bf16x8*)&tr[row][c0 + 8];
      short* d = Vw + ((size_t)bh * DKEY + row) * S_LEN + sbase + c0;
      *(bf16x8*)&d[0] = x0;
      *(bf16x8*)&d[8] = x1;
    }
    return;
  }

  short* outw = (z == 0) ? Qw : Kw;
#pragma unroll
  for (int nj = 0; nj < 4; ++nj) {
    const int n = n0 + wc + nj * 16 + l15;
    const float bval = bias[n];
    const int h = n >> 6, dk = n & 63;
    const int bh = b * NHEAD + h;
#pragma unroll
    for (int ti = 0; ti < 4; ++ti) {
#pragma unroll
      for (int r = 0; r < 4; ++r) {
        const int s = sbase + ti * 16 + quad * 4 + r;
        float val = acc[ti][nj][r] + bval;
        const float cosv = rope[((size_t)b * S_LEN + s) * DKEY + (dk | 1)];
        const float sinv = rope[((size_t)b * S_LEN + s) * DKEY + (dk & ~1)];
        const float partner = __shfl_xor(val, 1);
        val = (dk & 1) ? (val * cosv + partner * sinv)
                       : (val * cosv - partner * sinv);
        // (1/8)*log2(e): softmax runs in exp2 domain inside attn_kernel.
        if (z == 0) val *= 0.18033688011112042f;
        outw[((size_t)bh * S_LEN + s) * DKEY + dk] = f2bf(val);
      }
    }
  }
}

// ---------------------------------------------------------------------------
// Kernel 2: causal flash attention (unchanged from previous round).
// ---------------------------------------------------------------------------
__global__ __launch_bounds__(256, 4) void attn_kernel(
    const short* __restrict__ Qw, const short* __restrict__ Kw,
    const short* __restrict__ Vw, const float* __restrict__ v_mask,
    short* __restrict__ Ow) {
  __shared__ short Kt[2][64][64];
  __shared__ short Vt[2][64][64];
  __shared__ short Sb[4][16][64];   // XOR chunk-swizzled: chunk ^= (row & 7)

  const int t = threadIdx.x;
  const int w = t >> 6;
  const int lane = t & 63;
  const int quad = lane >> 4;
  const int l15 = lane & 15;
  const int x8 = l15 & 7;
  const int bh = blockIdx.y;
  const int b = bh >> 4;
  const int h = bh & 15;

  // balanced chunk map: co-resident blocks get {x, x^31, x^16, x^31^16}
  int c = blockIdx.x;
  const int jj = blockIdx.y >> 3;
  if (jj & 1) c ^= 31;
  if (jj & 2) c ^= 16;

  const short* Kbase = Kw + (size_t)bh * S_LEN * DKEY;
  const short* Vbase = Vw + (size_t)bh * DKEY * S_LEN;
  const float* vmb = v_mask + (size_t)b * S_LEN;

  const int sRow = lane >> 3;
  const int sCh = (lane & 7) ^ sRow;

  const int qb = c * 64;
  const int qrow = qb + w * 16 + l15;

  const short* Qp = Qw + ((size_t)bh * S_LEN + qrow) * DKEY;
  const bf16x8 q_lo = *(const bf16x8*)(Qp + quad * 8);
  const bf16x8 q_hi = *(const bf16x8*)(Qp + 32 + quad * 8);

  // block-uniform v_mask shortcut: exact iff every element == 1.0f
  float s32 = 0.f;
  {
    const float4* vm4 = (const float4*)vmb;
#pragma unroll
    for (int i = 0; i < 8; ++i) {
      const float4 a = vm4[lane * 8 + i];
      s32 += a.x + a.y + a.z + a.w;
    }
  }
  const bool vmall = __all(s32 == 32.0f);

  float m_i = -1.0e30f, l_i = 0.f;
  f32x4 acc[4] = {};

  const int niter = c + 1;
#pragma unroll
  for (int i = 0; i < 2; ++i) {
    const int kr = w * 16 + i * 8 + sRow;
    gl_lds16(Kbase + (size_t)kr * DKEY + sCh * 8, &Kt[0][w * 16 + i * 8][0]);
    gl_lds16(Vbase + (size_t)kr * S_LEN + sCh * 8, &Vt[0][w * 16 + i * 8][0]);
  }
  int cur = 0;
  for (int it = 0; it < niter; ++it) {
    const int j0 = it * 64;
    __syncthreads();
    if (it + 1 < niter) {
      const int jn = j0 + 64;
#pragma unroll
      for (int i = 0; i < 2; ++i) {
        const int kr = w * 16 + i * 8 + sRow;
        gl_lds16(Kbase + (size_t)(jn + kr) * DKEY + sCh * 8,
                 &Kt[cur ^ 1][w * 16 + i * 8][0]);
        gl_lds16(Vbase + (size_t)kr * S_LEN + jn + sCh * 8,
                 &Vt[cur ^ 1][w * 16 + i * 8][0]);
      }
    }
    bf16x8 ka[4][2];
#pragma unroll
    for (int kt = 0; kt < 4; ++kt) {
      ka[kt][0] = *(const bf16x8*)&Kt[cur][kt * 16 + l15][(quad ^ x8) * 8];
      ka[kt][1] = *(const bf16x8*)&Kt[cur][kt * 16 + l15][((4 + quad) ^ x8) * 8];
    }
    f32x4 sv[4];
    __builtin_amdgcn_s_setprio(1);
#pragma unroll
    for (int kt = 0; kt < 4; ++kt) {
      f32x4 s = {};
      s = __builtin_amdgcn_mfma_f32_16x16x32_bf16(ka[kt][0], q_lo, s, 0, 0, 0);
      s = __builtin_amdgcn_mfma_f32_16x16x32_bf16(ka[kt][1], q_hi, s, 0, 0, 0);
      sv[kt] = s;
    }
    __builtin_amdgcn_s_setprio(0);
    if (!vmall) {
#pragma unroll
      for (int kt = 0; kt < 4; ++kt) {
        const float4 vm = *(const float4*)&vmb[j0 + kt * 16 + quad * 4];
#pragma unroll
        for (int r = 0; r < 4; ++r)
          sv[kt][r] += (vm[r] - 1.0f) * 1.0e12f;
      }
    }
    if (it == c) {  // diagonal tile: only place causal mask can trigger
#pragma unroll
      for (int kt = 0; kt < 4; ++kt)
#pragma unroll
        for (int r = 0; r < 4; ++r) {
          const int kc = j0 + kt * 16 + quad * 4 + r;
          if (kc > qrow) sv[kt][r] = -1.0e12f;
        }
    }
    float mk[4];
#pragma unroll
    for (int kt = 0; kt < 4; ++kt)
      mk[kt] = fmaxf(fmaxf(sv[kt][0], sv[kt][1]), fmaxf(sv[kt][2], sv[kt][3]));
    const float mloc = fmaxf(fmaxf(mk[0], mk[1]), fmaxf(mk[2], mk[3]));
    float mt = fmaxf(mloc, __shfl_xor(mloc, 16));
    mt = fmaxf(mt, __shfl_xor(mt, 32));
    if (!__all(mt <= m_i + 8.0f)) {
      const float mn = fmaxf(m_i, mt);
      const float alpha = EX2(m_i - mn);
      l_i *= alpha;
#pragma unroll
      for (int dt = 0; dt < 4; ++dt)
#pragma unroll
        for (int r = 0; r < 4; ++r) acc[dt][r] *= alpha;
      m_i = mn;
    }
    float sl = 0.f;
#pragma unroll
    for (int kt = 0; kt < 4; ++kt)
#pragma unroll
      for (int r = 0; r < 4; ++r) {
        sv[kt][r] = EX2(sv[kt][r] - m_i);
        sl += sv[kt][r];
      }
    sl += __shfl_xor(sl, 16);
    sl += __shfl_xor(sl, 32);
    l_i += sl;
#pragma unroll
    for (int kt = 0; kt < 4; ++kt) {
      uint2 pw;
      pw.x = pk2bf(sv[kt][0], sv[kt][1]);
      pw.y = pk2bf(sv[kt][2], sv[kt][3]);
      *(uint2*)&Sb[w][l15][(((2 * kt + (quad >> 1)) ^ x8) * 8) + (quad & 1) * 4] = pw;
    }
    asm volatile("s_waitcnt lgkmcnt(0)" ::: "memory");
    const bf16x8 pf0 = *(const bf16x8*)&Sb[w][l15][(quad ^ x8) * 8];
    const bf16x8 pf1 = *(const bf16x8*)&Sb[w][l15][((4 + quad) ^ x8) * 8];
    __builtin_amdgcn_s_setprio(1);
#pragma unroll
    for (int dt = 0; dt < 4; ++dt) {
      const bf16x8 va0 =
          *(const bf16x8*)&Vt[cur][dt * 16 + l15][(quad ^ x8) * 8];
      acc[dt] = __builtin_amdgcn_mfma_f32_16x16x32_bf16(va0, pf0, acc[dt], 0, 0, 0);
      const bf16x8 va1 =
          *(const bf16x8*)&Vt[cur][dt * 16 + l15][((4 + quad) ^ x8) * 8];
      acc[dt] = __builtin_amdgcn_mfma_f32_16x16x32_bf16(va1, pf1, acc[dt], 0, 0, 0);
    }
    __builtin_amdgcn_s_setprio(0);
    cur ^= 1;
  }
  const float inv = 1.0f / l_i;
#pragma unroll
  for (int dt = 0; dt < 4; ++dt) {
    uint2 ov;
    ov.x = pk2bf(acc[dt][0] * inv, acc[dt][1] * inv);
    ov.y = pk2bf(acc[dt][2] * inv, acc[dt][3] * inv);
    *(uint2*)&Sb[w][l15][(((2 * dt + (quad >> 1)) ^ x8) * 8) + (quad & 1) * 4] = ov;
  }
  asm volatile("s_waitcnt lgkmcnt(0)" ::: "memory");
  const int qr2 = lane >> 2;
  const int cc2 = lane & 3;
  const bf16x8 o0 = *(const bf16x8*)&Sb[w][qr2][((2 * cc2) ^ (qr2 & 7)) * 8];
  const bf16x8 o1 = *(const bf16x8*)&Sb[w][qr2][((2 * cc2 + 1) ^ (qr2 & 7)) * 8];
  short* dst =
      Ow + ((size_t)(b * S_LEN + qb + w * 16 + qr2)) * DMODEL + h * DKEY + cc2 * 16;
  *(bf16x8*)&dst[0] = o0;
  *(bf16x8*)&dst[8] = o1;
}

// ---------------------------------------------------------------------------
// Kernel 3: output projection. Grid is only 256 blocks = 1 block/CU (zero
// TLP), so use a 4-deep ring (3-iteration lookahead ~ full HBM latency).
// ---------------------------------------------------------------------------
__global__ __launch_bounds__(256) void gemm_out(
    const short* __restrict__ A, const short* __restrict__ Wz,
    const float* __restrict__ bias, float* __restrict__ out) {
  __shared__ char smem[65536];   // 4 ring buffers x (A 8KB + B 8KB)

  const int m0 = blockIdx.x * 128, n0 = blockIdx.y * 128;
  const int t = threadIdx.x;
  const int lane = t & 63;
  const int w = t >> 6;
  const int quad = lane >> 4;
  const int l15 = lane & 15;
  const int wr = (w >> 1) * 64, wc = (w & 1) * 64;
  const int rswz = (quad ^ ((l15 >> 1) & 3)) * 8;

  const short* Abase = A + (size_t)m0 * DMODEL;
  const short* Bbase = Wz + (size_t)n0 * DMODEL;

  f32x4 acc[4][4] = {};

  // prologue: tiles 0..2 into ring slots 0..2
#pragma unroll
  for (int p = 0; p < 3; ++p) {
    stage_tile32(Abase + p * 32, (short(*)[32])(smem + p * 16384), w, lane);
    stage_tile32(Bbase + p * 32, (short(*)[32])(smem + p * 16384 + 8192), w, lane);
  }

  unsigned o0 = 0, o1 = 16384, o2 = 32768, o3 = 49152;  // cur, +1, +2, +3
  for (int it = 0; it < 32; ++it) {
    if (it < 29) {
      const int kt = (it + 3) * 32;
      stage_tile32(Abase + kt, (short(*)[32])(smem + o3), w, lane);
      stage_tile32(Bbase + kt, (short(*)[32])(smem + o3 + 8192), w, lane);
    }
    if (it < 29)       asm volatile("s_waitcnt vmcnt(12)" ::: "memory");
    else if (it == 29) asm volatile("s_waitcnt vmcnt(8)" ::: "memory");
    else if (it == 30) asm volatile("s_waitcnt vmcnt(4)" ::: "memory");
    else               asm volatile("s_waitcnt vmcnt(0)" ::: "memory");
    __builtin_amdgcn_s_barrier();
    short (*As)[32] = (short(*)[32])(smem + o0);
    short (*Bs)[32] = (short(*)[32])(smem + o0 + 8192);
    bf16x8 bf[4], af[4];
#pragma unroll
    for (int nj = 0; nj < 4; ++nj)
      bf[nj] = *(const bf16x8*)&Bs[wc + nj * 16 + l15][rswz];
#pragma unroll
    for (int mi = 0; mi < 4; ++mi)
      af[mi] = *(const bf16x8*)&As[wr + mi * 16 + l15][rswz];
#pragma unroll
    for (int mi = 0; mi < 4; ++mi)
#pragma unroll
      for (int nj = 0; nj < 4; ++nj)
        acc[mi][nj] =
            __builtin_amdgcn_mfma_f32_16x16x32_bf16(af[mi], bf[nj], acc[mi][nj], 0, 0, 0);
    asm volatile("s_waitcnt lgkmcnt(0)" ::: "memory");
    __builtin_amdgcn_s_barrier();
    const unsigned tmp = o0; o0 = o1; o1 = o2; o2 = o3; o3 = tmp;
  }
#pragma unroll
  for (int nj = 0; nj < 4; ++nj) {
    const int n = n0 + wc + nj * 16 + l15;
    const float bval = bias[n];
#pragma unroll
    for (int ti = 0; ti < 4; ++ti)
#pragma unroll
      for (int r = 0; r < 4; ++r) {
        const int m = m0 + wr + ti * 16 + quad * 4 + r;
        out[(size_t)m * DMODEL + n] = acc[ti][nj][r] + bval;
      }
  }
}

// ---------------------------------------------------------------------------
extern "C" void kernel_launch(void* const* d_in, const int* in_sizes, int n_in,
                              void* d_out, int out_size, void* d_ws,
                              size_t ws_size, hipStream_t stream) {
  const float* q      = (const float*)d_in[0];
  const float* k      = (const float*)d_in[1];
  const float* v      = (const float*)d_in[2];
  const float* rope   = (const float*)d_in[3];
  const float* v_mask = (const float*)d_in[5];
  const float* Wq = (const float*)d_in[6];
  const float* bq = (const float*)d_in[7];
  const float* Wk = (const float*)d_in[8];
  const float* bk = (const float*)d_in[9];
  const float* Wv = (const float*)d_in[10];
  const float* bv = (const float*)d_in[11];
  const float* Wo = (const float*)d_in[12];
  const float* bo = (const float*)d_in[13];
  float* out = (float*)d_out;

  short* ws = (short*)d_ws;
  short* Qw = ws;                  // [bh][s][dk] bf16, 8 MB
  short* Kw = ws + 4194304;        // [bh][s][dk] bf16, 8 MB
  short* Vw = ws + 8388608;        // [bh][dk][s] bf16, 8 MB
  short* Ow = ws + 12582912;       // [b][s][dmodel] bf16, 8 MB
  short* Wt = ws + 16777216;       // 4x [n][k] bf16, 8 MB
  short* Xb = ws + 20971520;       // 3x [m][k] bf16, 24 MB  (total 64 MB)

  convert_x<<<dim3(4096, 3), 256, 0, stream>>>(q, k, v, Xb);
  convert_w<<<dim3(16, 16, 4), 256, 0, stream>>>(Wq, Wk, Wv, Wo, Wt);
  gemm_qkv<<<dim3(32, 8, 3), 256, 0, stream>>>(Xb, Wt, bq, bk, bv, rope,
                                               Qw, Kw, Vw);
  attn_kernel<<<dim3(32, 32), 256, 0, stream>>>(Qw, Kw, Vw, v_mask, Ow);
  gemm_out<<<dim3(32, 8), 256, 0, stream>>>(Ow, Wt + 3145728, bo, out);
}